// Round 16
// baseline (202.848 us; speedup 1.0000x reference)
//
#include <hip/hip_runtime.h>
#include <hip/hip_bf16.h>
#include <math.h>

#define DIM    384
#define NHEAD  8
#define HDIM   48
#define NTOK   2048              // tokens per batch (8*16*16)
#define BATCH  2
#define TOKS   (BATCH * NTOK)    // 4096
#define HIDDEN 1536

typedef __bf16 bf16x8 __attribute__((ext_vector_type(8)));
typedef float  f32x4  __attribute__((ext_vector_type(4)));
typedef unsigned short u16;

union bfu { __hip_bfloat16 h; u16 u; };

__device__ __forceinline__ void load_lds16(const void* g, void* l) {
    __builtin_amdgcn_global_load_lds(
        (const __attribute__((address_space(1))) void*)g,
        (__attribute__((address_space(3))) void*)l, 16, 0, 0);
}

// ---------------------------------------------------------------------------
// prep: 4 weight cast+transposes (blocks 0..1727) + fused input transpose/LN1
// (blocks 1728..1855) in ONE dispatch.
// ---------------------------------------------------------------------------
__global__ __launch_bounds__(256) void prep(
    const float* __restrict__ Wqkv, const float* __restrict__ Wo,
    const float* __restrict__ W1,   const float* __restrict__ W2,
    __hip_bfloat16* __restrict__ WqkvT, __hip_bfloat16* __restrict__ WoT,
    __hip_bfloat16* __restrict__ W1T,   __hip_bfloat16* __restrict__ W2T,
    const float* __restrict__ x, const float* __restrict__ g,
    const float* __restrict__ bta,
    float* __restrict__ hOut, __hip_bfloat16* __restrict__ y) {
    __shared__ __align__(16) char smem[384 * 33 * 4];
    int id = blockIdx.x;
    int tid = threadIdx.x;
    if (id < 1728) {
        float (*t)[33] = (float(*)[33])smem;
        const float* src; __hip_bfloat16* dst; int R, C;
        if (id < 432)       { src = Wqkv; dst = WqkvT; R = 384;  C = 1152; }
        else if (id < 576)  { id -= 432;  src = Wo;    dst = WoT;  R = 384;  C = 384; }
        else if (id < 1152) { id -= 576;  src = W1;    dst = W1T;  R = 384;  C = 1536; }
        else                { id -= 1152; src = W2;    dst = W2T;  R = 1536; C = 384; }
        int tc = C / 32;
        int i0 = (id / tc) * 32, j0 = (id % tc) * 32;
        int tx = tid & 31, ty = tid >> 5;
#pragma unroll
        for (int k = 0; k < 32; k += 8)
            t[ty + k][tx] = src[(size_t)(i0 + ty + k) * C + j0 + tx];
        __syncthreads();
#pragma unroll
        for (int k = 0; k < 32; k += 8)
            dst[(size_t)(j0 + ty + k) * R + i0 + tx] = __float2bfloat16(t[tx][ty + k]);
    } else {
        float* t = (float*)smem;
        int id2 = id - 1728;
        int n0 = (id2 & 63) * 32, b = id2 >> 6;
        const float* xb = x + (size_t)b * DIM * NTOK;
        for (int idx = tid; idx < 384 * 32; idx += 256) {
            int c = idx >> 5, n = idx & 31;
            t[c * 33 + n] = xb[(size_t)c * NTOK + n0 + n];
        }
        __syncthreads();
        int wid = tid >> 6, lane = tid & 63;
#pragma unroll
        for (int it = 0; it < 8; ++it) {
            int tl = it * 4 + wid;
            float v[6];
            float s = 0.f;
#pragma unroll
            for (int i = 0; i < 6; ++i) { v[i] = t[(lane + 64 * i) * 33 + tl]; s += v[i]; }
#pragma unroll
            for (int o = 32; o; o >>= 1) s += __shfl_xor(s, o, 64);
            float mu = s * (1.f / DIM);
            float s2 = 0.f;
#pragma unroll
            for (int i = 0; i < 6; ++i) { float d = v[i] - mu; s2 += d * d; }
#pragma unroll
            for (int o = 32; o; o >>= 1) s2 += __shfl_xor(s2, o, 64);
            float r = rsqrtf(s2 * (1.f / DIM) + 1e-6f);
            size_t tok = (size_t)b * NTOK + n0 + tl;
#pragma unroll
            for (int i = 0; i < 6; ++i) {
                int c = lane + 64 * i;
                hOut[tok * DIM + c] = v[i];
                y[tok * DIM + c] = __float2bfloat16((v[i] - mu) * r * g[c] + bta[c]);
            }
        }
    }
}

// ---------------------------------------------------------------------------
// LayerNorm (LN2): one wave per token, 4 tokens/block. f32 in, bf16 out.
// ---------------------------------------------------------------------------
__global__ __launch_bounds__(256) void ln_kernel(const float* __restrict__ x,
                                                 const float* __restrict__ g,
                                                 const float* __restrict__ bta,
                                                 __hip_bfloat16* __restrict__ y) {
    int wid = threadIdx.x >> 6, lane = threadIdx.x & 63;
    int tok = blockIdx.x * 4 + wid;
    const float* xr = x + (size_t)tok * DIM;
    float v[6];
    float s = 0.f;
#pragma unroll
    for (int i = 0; i < 6; ++i) { v[i] = xr[lane + 64 * i]; s += v[i]; }
#pragma unroll
    for (int o = 32; o; o >>= 1) s += __shfl_xor(s, o, 64);
    float mu = s * (1.f / DIM);
    float s2 = 0.f;
#pragma unroll
    for (int i = 0; i < 6; ++i) { float d = v[i] - mu; s2 += d * d; }
#pragma unroll
    for (int o = 32; o; o >>= 1) s2 += __shfl_xor(s2, o, 64);
    float r = rsqrtf(s2 * (1.f / DIM) + 1e-6f);
    __hip_bfloat16* yr = y + (size_t)tok * DIM;
#pragma unroll
    for (int i = 0; i < 6; ++i) {
        int c = lane + 64 * i;
        yr[c] = __float2bfloat16((v[i] - mu) * r * g[c] + bta[c]);
    }
}

// ---------------------------------------------------------------------------
// 64x64 bf16 MFMA GEMM, BK=128 (four stride-32 sub-blocks), 256 threads =
// 4 waves x 32x32 out (known-good config).
// TRANSOUT: write f32 out[b][c][n] transposed via LDS tile (N must be 384).
// QKV: cols <768 -> bf16 C[M,1152]; cols >=768 (V) -> permuted VT directly.
// V permutation (matches attn 4-way key-split): within each 128-key chunk,
// stored pos = (kk & ~31) + ((kk & 15) << 1) + ((kk >> 4) & 1).
// ---------------------------------------------------------------------------
template<bool GELU, bool BF16OUT, bool TRANSOUT, bool QKV>
__global__ __launch_bounds__(256) void gemm_mfma(
    const __hip_bfloat16* __restrict__ A,    // [M,K]
    const __hip_bfloat16* __restrict__ BT,   // [N,K]
    const float* __restrict__ bias,
    const float* __restrict__ res,
    void* __restrict__ Cout,
    int M, int N, int K,
    __hip_bfloat16* __restrict__ vtout) {
    __shared__ __align__(16) u16 As[4][64 * 32];
    __shared__ __align__(16) u16 Bs[4][64 * 32];
    int bm = blockIdx.y * 64, bn = blockIdx.x * 64;
    int tid = threadIdx.x;
    int w = tid >> 6, l = tid & 63;
    int m0 = (w >> 1) * 32, n0 = (w & 1) * 32;
    int lm = l & 15, ksel = l >> 4;

    int row = tid >> 2, c16 = tid & 3;
    const __hip_bfloat16* ga = A  + (size_t)(bm + row) * K + c16 * 8;
    const __hip_bfloat16* gb = BT + (size_t)(bn + row) * K + c16 * 8;

    f32x4 acc[2][2] = {};
    for (int k0 = 0; k0 < K; k0 += 128) {
#pragma unroll
        for (int kk = 0; kk < 4; ++kk) {
            load_lds16(ga + k0 + kk * 32, &As[kk][tid * 8]);
            load_lds16(gb + k0 + kk * 32, &Bs[kk][tid * 8]);
        }
        __syncthreads();
#pragma unroll
        for (int kk = 0; kk < 4; ++kk) {
            bf16x8 af0 = *(const bf16x8*)&As[kk][(m0 +      lm) * 32 + ksel * 8];
            bf16x8 af1 = *(const bf16x8*)&As[kk][(m0 + 16 + lm) * 32 + ksel * 8];
            bf16x8 bf0 = *(const bf16x8*)&Bs[kk][(n0 +      lm) * 32 + ksel * 8];
            bf16x8 bf1 = *(const bf16x8*)&Bs[kk][(n0 + 16 + lm) * 32 + ksel * 8];
            acc[0][0] = __builtin_amdgcn_mfma_f32_16x16x32_bf16(af0, bf0, acc[0][0], 0, 0, 0);
            acc[0][1] = __builtin_amdgcn_mfma_f32_16x16x32_bf16(af0, bf1, acc[0][1], 0, 0, 0);
            acc[1][0] = __builtin_amdgcn_mfma_f32_16x16x32_bf16(af1, bf0, acc[1][0], 0, 0, 0);
            acc[1][1] = __builtin_amdgcn_mfma_f32_16x16x32_bf16(af1, bf1, acc[1][1], 0, 0, 0);
        }
        __syncthreads();
    }

    if constexpr (TRANSOUT) {
        __shared__ float ct[64 * 65];
#pragma unroll
        for (int i = 0; i < 2; ++i)
#pragma unroll
            for (int j = 0; j < 2; ++j)
#pragma unroll
                for (int r = 0; r < 4; ++r) {
                    int ml = m0 + i * 16 + ksel * 4 + r;
                    int cl = n0 + j * 16 + lm;
                    float v = acc[i][j][r];
                    if (bias) v += bias[bn + cl];
                    if (res)  v += res[(size_t)(bm + ml) * N + bn + cl];
                    ct[ml * 65 + cl] = v;
                }
        __syncthreads();
        int bb = bm >> 11, nb = bm & (NTOK - 1);
        float* outp = (float*)Cout + (size_t)bb * DIM * NTOK + nb;
#pragma unroll
        for (int cl = w; cl < 64; cl += 4)
            outp[(size_t)(bn + cl) * NTOK + l] = ct[l * 65 + cl];
    } else {
#pragma unroll
        for (int i = 0; i < 2; ++i)
#pragma unroll
            for (int j = 0; j < 2; ++j)
#pragma unroll
                for (int r = 0; r < 4; ++r) {
                    int rg = bm + m0 + i * 16 + ksel * 4 + r;
                    int cg = bn + n0 + j * 16 + lm;
                    float v = acc[i][j][r];
                    if (bias) v += bias[cg];
                    if (GELU) v = 0.5f * v * (1.f + erff(v * 0.7071067811865475f));
                    if (res)  v += res[(size_t)rg * N + cg];
                    if constexpr (QKV) {
                        if (cg < 768) {
                            ((__hip_bfloat16*)Cout)[(size_t)rg * 1152 + cg] = __float2bfloat16(v);
                        } else {
                            int c = cg - 768, hh = c / 48, dd = c - hh * 48;
                            int bb = rg >> 11, n = rg & (NTOK - 1);
                            int kk = n & 127;
                            int pos = (kk & ~31) + ((kk & 15) << 1) + ((kk >> 4) & 1);
                            vtout[((size_t)(bb * NHEAD + hh) * 48 + dd) * 2048
                                  + (n & ~127) + pos] = __float2bfloat16(v);
                        }
                    } else if constexpr (BF16OUT) {
                        ((__hip_bfloat16*)Cout)[(size_t)rg * N + cg] = __float2bfloat16(v);
                    } else {
                        ((float*)Cout)[(size_t)rg * N + cg] = v;
                    }
                }
    }
}

// ---------------------------------------------------------------------------
// bf16 MFMA flash attention, 128-key tiles, one-pass softmax, 512 threads =
// 8 waves: wave w -> key-quarter kh=w&3 (32 keys), q-half qc=w>>2 (32 rows).
// vs the 2-way split: kf reads 8->4, vf reads 6->3 (register-cached, reused
// across both q-subtiles). Q frags (4) register-cached; Ps overlays Qs.
// End: 4-way kh merge via LDS scratch (reusing Ks for O, Vs for l),
// staged per qc to fit scratch.
// ---------------------------------------------------------------------------
#define ATK 128
#define PSTR 136   // row stride in u16; rows 16B-aligned
__global__ __launch_bounds__(512) void attn_mfma(
    const u16* __restrict__ qkv,             // bf16 [TOKS][1152] (Q,K valid)
    const u16* __restrict__ vt,              // bf16 [16][48][2048] (permuted keys)
    __hip_bfloat16* __restrict__ outp) {     // bf16 [TOKS][DIM]
    __shared__ __align__(16) u16 PQ[64 * PSTR];   // Qs (stride 72) then Ps
    __shared__ __align__(16) u16 Ks[128 * 72];
    __shared__ __align__(16) u16 Vs[48 * PSTR];
    const int q0 = blockIdx.x * 64;
    const int h = blockIdx.y, b = blockIdx.z;
    const int tid = threadIdx.x;
    const int w = tid >> 6, l = tid & 63, lm = l & 15, quad = l >> 4;
    const int qc = w >> 2, kh = w & 3;

    // zero k-pads (cols 48..63)
    for (int idx = tid; idx < 128; idx += 512) {
        int r = idx >> 1, c = idx & 1;
        *(uint4*)&PQ[r * 72 + 48 + c * 8] = uint4{0, 0, 0, 0};
    }
    for (int idx = tid; idx < 256; idx += 512) {
        int r = idx >> 1, c = idx & 1;
        *(uint4*)&Ks[r * 72 + 48 + c * 8] = uint4{0, 0, 0, 0};
    }
    // stage Q tile (64 rows x 48) at stride 72
    const u16* qbase = qkv + (size_t)(b * NTOK + q0) * 1152 + h * 48;
    for (int idx = tid; idx < 384; idx += 512) {
        int r = idx / 6, c = idx % 6;
        *(uint4*)&PQ[r * 72 + c * 8] = *(const uint4*)(qbase + (size_t)r * 1152 + c * 8);
    }
    __syncthreads();

    // register-cache Q fragments: rows qc*32 + qsub*16 + lm
    bf16x8 aq[2][2];
#pragma unroll
    for (int qsub = 0; qsub < 2; ++qsub) {
        aq[qsub][0] = *(const bf16x8*)&PQ[(qc * 32 + qsub * 16 + lm) * 72 +  0 + quad * 8];
        aq[qsub][1] = *(const bf16x8*)&PQ[(qc * 32 + qsub * 16 + lm) * 72 + 32 + quad * 8];
    }

    float l_i[8] = {};            // [qsub*4 + r]
    f32x4 o_acc[2][3] = {};       // [qsub][nt]

    const u16* kbase = qkv + (size_t)(b * NTOK) * 1152 + 384 + h * 48;
    const u16* vbase = vt + (size_t)(b * NHEAD + h) * 48 * 2048;
    const float sc2 = 0.14433756729740643f * 1.4426950408889634f;  // scale*log2e

    for (int kt = 0; kt < NTOK / ATK; ++kt) {
        __syncthreads();
        // stage K: 128 rows x 48 (768 uint4)
#pragma unroll
        for (int idx = tid; idx < 768; idx += 512) {
            int r = idx / 6, c = idx % 6;
            *(uint4*)&Ks[r * 72 + c * 8] =
                *(const uint4*)(kbase + (size_t)(kt * ATK + r) * 1152 + c * 8);
        }
        // stage V (permuted key order): 48 dims x 128 positions (768 uint4)
#pragma unroll
        for (int idx = tid; idx < 768; idx += 512) {
            int d = idx >> 4, c = idx & 15;
            *(uint4*)&Vs[d * PSTR + c * 8] =
                *(const uint4*)(vbase + (size_t)d * 2048 + kt * ATK + c * 8);
        }
        __syncthreads();

        // S = Q K^T: wave's keys = kh*32 + nt*16 + lm (nt in 0..1)
        f32x4 s[2][2];   // [qsub][nt]
#pragma unroll
        for (int nt = 0; nt < 2; ++nt) {
            int krow = (kh * 32 + nt * 16 + lm) * 72;
            bf16x8 kf0 = *(const bf16x8*)&Ks[krow +  0 + quad * 8];
            bf16x8 kf1 = *(const bf16x8*)&Ks[krow + 32 + quad * 8];
#pragma unroll
            for (int qsub = 0; qsub < 2; ++qsub) {
                f32x4 t = {};
                t = __builtin_amdgcn_mfma_f32_16x16x32_bf16(aq[qsub][0], kf0, t, 0, 0, 0);
                t = __builtin_amdgcn_mfma_f32_16x16x32_bf16(aq[qsub][1], kf1, t, 0, 0, 0);
                s[qsub][nt] = t;
            }
        }

        // P = exp2(S*sc2); store pair (nt=0,1) contiguously at pos kh*32+lm*2
#pragma unroll
        for (int qsub = 0; qsub < 2; ++qsub)
#pragma unroll
            for (int r = 0; r < 4; ++r) {
                float p0 = exp2f(s[qsub][0][r] * sc2);
                float p1 = exp2f(s[qsub][1][r] * sc2);
                l_i[qsub * 4 + r] += p0 + p1;
                bfu c0, c1; c0.h = __float2bfloat16(p0); c1.h = __float2bfloat16(p1);
                unsigned int packed = (unsigned int)c0.u | ((unsigned int)c1.u << 16);
                *(unsigned int*)&PQ[(qc * 32 + qsub * 16 + quad * 4 + r) * PSTR
                                    + kh * 32 + lm * 2] = packed;
            }

        // O += P V over wave's 32 stored positions; vf cached across qsub
        bf16x8 vf[3];
#pragma unroll
        for (int nt = 0; nt < 3; ++nt)
            vf[nt] = *(const bf16x8*)&Vs[(nt * 16 + lm) * PSTR + kh * 32 + quad * 8];
#pragma unroll
        for (int qsub = 0; qsub < 2; ++qsub) {
            bf16x8 pf = *(const bf16x8*)&PQ[(qc * 32 + qsub * 16 + lm) * PSTR
                                            + kh * 32 + quad * 8];
#pragma unroll
            for (int nt = 0; nt < 3; ++nt)
                o_acc[qsub][nt] = __builtin_amdgcn_mfma_f32_16x16x32_bf16(
                    pf, vf[nt], o_acc[qsub][nt], 0, 0, 0);
        }
    }

    // ---- 4-way kh merge, staged per qc ----
    float* oScr = (float*)Ks;   // 4608 f32: [slot kh-1][lane][24]
    float* lScr = (float*)Vs;   // 3264 f32: [qc][slot kh-1][lane][8]
    __syncthreads();
    if (kh > 0) {
        float* lb = &lScr[qc * 1536 + (kh - 1) * 512 + l * 8];
        *(f32x4*)lb       = *(f32x4*)&l_i[0];
        *(f32x4*)(lb + 4) = *(f32x4*)&l_i[4];
        if (qc == 0) {
            float* ob = &oScr[(kh - 1) * 1536 + l * 24];
#pragma unroll
            for (int qsub = 0; qsub < 2; ++qsub)
#pragma unroll
                for (int nt = 0; nt < 3; ++nt)
                    *(f32x4*)(ob + (qsub * 3 + nt) * 4) = o_acc[qsub][nt];
        }
    }
    __syncthreads();
    if (kh == 0 && qc == 0) {
#pragma unroll
        for (int sct = 0; sct < 3; ++sct) {
            float* ob = &oScr[sct * 1536 + l * 24];
            float* lb = &lScr[0 * 1536 + sct * 512 + l * 8];
#pragma unroll
            for (int qsub = 0; qsub < 2; ++qsub)
#pragma unroll
                for (int nt = 0; nt < 3; ++nt)
                    o_acc[qsub][nt] += *(f32x4*)(ob + (qsub * 3 + nt) * 4);
            f32x4 la = *(f32x4*)lb, lbv = *(f32x4*)(lb + 4);
#pragma unroll
            for (int r = 0; r < 4; ++r) { l_i[r] += la[r]; l_i[4 + r] += lbv[r]; }
        }
#pragma unroll
        for (int qsub = 0; qsub < 2; ++qsub)
#pragma unroll
            for (int r = 0; r < 4; ++r) {
                float lsum = l_i[qsub * 4 + r];
#pragma unroll
                for (int o = 8; o; o >>= 1) lsum += __shfl_xor(lsum, o, 64);
                float inv = 1.f / lsum;
#pragma unroll
                for (int nt = 0; nt < 3; ++nt)
                    outp[(size_t)(b * NTOK + q0 + 0 * 32 + qsub * 16 + quad * 4 + r) * DIM
                         + h * 48 + nt * 16 + lm]
                        = __float2bfloat16(o_acc[qsub][nt][r] * inv);
            }
    }
    __syncthreads();
    if (kh > 0 && qc == 1) {
        float* ob = &oScr[(kh - 1) * 1536 + l * 24];
#pragma unroll
        for (int qsub = 0; qsub < 2; ++qsub)
#pragma unroll
            for (int nt = 0; nt < 3; ++nt)
                *(f32x4*)(ob + (qsub * 3 + nt) * 4) = o_acc[qsub][nt];
    }
    __syncthreads();
    if (kh == 0 && qc == 1) {
#pragma unroll
        for (int sct = 0; sct < 3; ++sct) {
            float* ob = &oScr[sct * 1536 + l * 24];
            float* lb = &lScr[1 * 1536 + sct * 512 + l * 8];
#pragma unroll
            for (int qsub = 0; qsub < 2; ++qsub)
#pragma unroll
                for (int nt = 0; nt < 3; ++nt)
                    o_acc[qsub][nt] += *(f32x4*)(ob + (qsub * 3 + nt) * 4);
            f32x4 la = *(f32x4*)lb, lbv = *(f32x4*)(lb + 4);
#pragma unroll
            for (int r = 0; r < 4; ++r) { l_i[r] += la[r]; l_i[4 + r] += lbv[r]; }
        }
#pragma unroll
        for (int qsub = 0; qsub < 2; ++qsub)
#pragma unroll
            for (int r = 0; r < 4; ++r) {
                float lsum = l_i[qsub * 4 + r];
#pragma unroll
                for (int o = 8; o; o >>= 1) lsum += __shfl_xor(lsum, o, 64);
                float inv = 1.f / lsum;
#pragma unroll
                for (int nt = 0; nt < 3; ++nt)
                    outp[(size_t)(b * NTOK + q0 + 1 * 32 + qsub * 16 + quad * 4 + r) * DIM
                         + h * 48 + nt * 16 + lm]
                        = __float2bfloat16(o_acc[qsub][nt][r] * inv);
            }
    }
}

// ---------------------------------------------------------------------------
extern "C" void kernel_launch(void* const* d_in, const int* in_sizes, int n_in,
                              void* d_out, int out_size, void* d_ws, size_t ws_size,
                              hipStream_t stream) {
    const float* x    = (const float*)d_in[0];
    const float* g1   = (const float*)d_in[1];
    const float* b1   = (const float*)d_in[2];
    const float* Wqkv = (const float*)d_in[3];
    const float* Wo   = (const float*)d_in[4];
    const float* bo   = (const float*)d_in[5];
    const float* g2   = (const float*)d_in[6];
    const float* b2   = (const float*)d_in[7];
    const float* W1   = (const float*)d_in[8];
    const float* b1m  = (const float*)d_in[9];
    const float* W2   = (const float*)d_in[10];
    const float* b2m  = (const float*)d_in[11];
    float* out = (float*)d_out;

    char* p = (char*)d_ws;
    float* bufH = (float*)p;                       p += (size_t)TOKS * DIM * 4;      // f32 [4096,384]
    char* qkvp = p;
    __hip_bfloat16* bufQKVb = (__hip_bfloat16*)p;  p += (size_t)TOKS * 3 * DIM * 2;  // bf16 [4096,1152]
    __hip_bfloat16* bufVT   = (__hip_bfloat16*)p;  p += (size_t)TOKS * DIM * 2;      // bf16 [16,48,2048]
    __hip_bfloat16* bufNb   = (__hip_bfloat16*)p;  p += (size_t)TOKS * DIM * 2;      // bf16 [4096,384]
    __hip_bfloat16* bufAb   = (__hip_bfloat16*)p;  p += (size_t)TOKS * DIM * 2;      // bf16 [4096,384]
    __hip_bfloat16* WqkvT   = (__hip_bfloat16*)p;  p += (size_t)3 * DIM * DIM * 2;   // [1152,384]
    __hip_bfloat16* WoT     = (__hip_bfloat16*)p;  p += (size_t)DIM * DIM * 2;       // [384,384]
    __hip_bfloat16* W1T     = (__hip_bfloat16*)p;  p += (size_t)HIDDEN * DIM * 2;    // [1536,384]
    __hip_bfloat16* W2T     = (__hip_bfloat16*)p;  p += (size_t)DIM * HIDDEN * 2;    // [384,1536]
    __hip_bfloat16* bufHIDb = (__hip_bfloat16*)qkvp;  // bf16 [4096,1536] overlays QKV+VT

    // 0. weight transposes + input transpose/LN1 (one dispatch)
    prep<<<1728 + 128, 256, 0, stream>>>(Wqkv, Wo, W1, W2, WqkvT, WoT, W1T, W2T,
                                         x, g1, b1, bufH, bufNb);
    // 1. QKV projection: Q,K -> bufQKVb; V -> bufVT (permuted) directly
    gemm_mfma<false, true, false, true><<<dim3(3 * DIM / 64, TOKS / 64), 256, 0, stream>>>(
        bufNb, WqkvT, nullptr, nullptr, bufQKVb, TOKS, 3 * DIM, DIM, bufVT);
    // 2. MFMA flash attention -> bf16 (512 threads, 4-way key split)
    attn_mfma<<<dim3(NTOK / 64, NHEAD, BATCH), 512, 0, stream>>>(
        (const u16*)bufQKVb, (const u16*)bufVT, bufAb);
    // 3. output projection + bias + residual -> f32 bufH (in place)
    gemm_mfma<false, false, false, false><<<dim3(DIM / 64, TOKS / 64), 256, 0, stream>>>(
        bufAb, WoT, bo, bufH, bufH, TOKS, DIM, DIM, nullptr);
    // 4. LN2 -> bf16
    ln_kernel<<<TOKS / 4, 256, 0, stream>>>(bufH, g2, b2, bufNb);
    // 5. MLP up + GELU -> bf16 hidden
    gemm_mfma<true, true, false, false><<<dim3(HIDDEN / 64, TOKS / 64), 256, 0, stream>>>(
        bufNb, W1T, b1m, nullptr, bufHIDb, TOKS, HIDDEN, DIM, nullptr);
    // 6. MLP down + bias + residual -> out (transposed write, f32)
    gemm_mfma<false, false, true, false><<<dim3(DIM / 64, TOKS / 64), 256, 0, stream>>>(
        bufHIDb, W2T, b2m, bufH, out, TOKS, DIM, HIDDEN, nullptr);
}

// Round 17
// 198.069 us; speedup vs baseline: 1.0241x; 1.0241x over previous
//
#include <hip/hip_runtime.h>
#include <hip/hip_bf16.h>
#include <math.h>

#define DIM    384
#define NHEAD  8
#define HDIM   48
#define NTOK   2048              // tokens per batch (8*16*16)
#define BATCH  2
#define TOKS   (BATCH * NTOK)    // 4096
#define HIDDEN 1536

typedef __bf16 bf16x8 __attribute__((ext_vector_type(8)));
typedef float  f32x4  __attribute__((ext_vector_type(4)));
typedef unsigned short u16;

union bfu { __hip_bfloat16 h; u16 u; };

__device__ __forceinline__ void load_lds16(const void* g, void* l) {
    __builtin_amdgcn_global_load_lds(
        (const __attribute__((address_space(1))) void*)g,
        (__attribute__((address_space(3))) void*)l, 16, 0, 0);
}

// ---------------------------------------------------------------------------
// prep: 4 weight cast+transposes (blocks 0..1727) + fused input transpose/LN1
// (blocks 1728..1855) in ONE dispatch.
// ---------------------------------------------------------------------------
__global__ __launch_bounds__(256) void prep(
    const float* __restrict__ Wqkv, const float* __restrict__ Wo,
    const float* __restrict__ W1,   const float* __restrict__ W2,
    __hip_bfloat16* __restrict__ WqkvT, __hip_bfloat16* __restrict__ WoT,
    __hip_bfloat16* __restrict__ W1T,   __hip_bfloat16* __restrict__ W2T,
    const float* __restrict__ x, const float* __restrict__ g,
    const float* __restrict__ bta,
    float* __restrict__ hOut, __hip_bfloat16* __restrict__ y) {
    __shared__ __align__(16) char smem[384 * 33 * 4];
    int id = blockIdx.x;
    int tid = threadIdx.x;
    if (id < 1728) {
        float (*t)[33] = (float(*)[33])smem;
        const float* src; __hip_bfloat16* dst; int R, C;
        if (id < 432)       { src = Wqkv; dst = WqkvT; R = 384;  C = 1152; }
        else if (id < 576)  { id -= 432;  src = Wo;    dst = WoT;  R = 384;  C = 384; }
        else if (id < 1152) { id -= 576;  src = W1;    dst = W1T;  R = 384;  C = 1536; }
        else                { id -= 1152; src = W2;    dst = W2T;  R = 1536; C = 384; }
        int tc = C / 32;
        int i0 = (id / tc) * 32, j0 = (id % tc) * 32;
        int tx = tid & 31, ty = tid >> 5;
#pragma unroll
        for (int k = 0; k < 32; k += 8)
            t[ty + k][tx] = src[(size_t)(i0 + ty + k) * C + j0 + tx];
        __syncthreads();
#pragma unroll
        for (int k = 0; k < 32; k += 8)
            dst[(size_t)(j0 + ty + k) * R + i0 + tx] = __float2bfloat16(t[tx][ty + k]);
    } else {
        float* t = (float*)smem;
        int id2 = id - 1728;
        int n0 = (id2 & 63) * 32, b = id2 >> 6;
        const float* xb = x + (size_t)b * DIM * NTOK;
        for (int idx = tid; idx < 384 * 32; idx += 256) {
            int c = idx >> 5, n = idx & 31;
            t[c * 33 + n] = xb[(size_t)c * NTOK + n0 + n];
        }
        __syncthreads();
        int wid = tid >> 6, lane = tid & 63;
#pragma unroll
        for (int it = 0; it < 8; ++it) {
            int tl = it * 4 + wid;
            float v[6];
            float s = 0.f;
#pragma unroll
            for (int i = 0; i < 6; ++i) { v[i] = t[(lane + 64 * i) * 33 + tl]; s += v[i]; }
#pragma unroll
            for (int o = 32; o; o >>= 1) s += __shfl_xor(s, o, 64);
            float mu = s * (1.f / DIM);
            float s2 = 0.f;
#pragma unroll
            for (int i = 0; i < 6; ++i) { float d = v[i] - mu; s2 += d * d; }
#pragma unroll
            for (int o = 32; o; o >>= 1) s2 += __shfl_xor(s2, o, 64);
            float r = rsqrtf(s2 * (1.f / DIM) + 1e-6f);
            size_t tok = (size_t)b * NTOK + n0 + tl;
#pragma unroll
            for (int i = 0; i < 6; ++i) {
                int c = lane + 64 * i;
                hOut[tok * DIM + c] = v[i];
                y[tok * DIM + c] = __float2bfloat16((v[i] - mu) * r * g[c] + bta[c]);
            }
        }
    }
}

// ---------------------------------------------------------------------------
// LayerNorm (LN2): one wave per token, 4 tokens/block. f32 in, bf16 out.
// ---------------------------------------------------------------------------
__global__ __launch_bounds__(256) void ln_kernel(const float* __restrict__ x,
                                                 const float* __restrict__ g,
                                                 const float* __restrict__ bta,
                                                 __hip_bfloat16* __restrict__ y) {
    int wid = threadIdx.x >> 6, lane = threadIdx.x & 63;
    int tok = blockIdx.x * 4 + wid;
    const float* xr = x + (size_t)tok * DIM;
    float v[6];
    float s = 0.f;
#pragma unroll
    for (int i = 0; i < 6; ++i) { v[i] = xr[lane + 64 * i]; s += v[i]; }
#pragma unroll
    for (int o = 32; o; o >>= 1) s += __shfl_xor(s, o, 64);
    float mu = s * (1.f / DIM);
    float s2 = 0.f;
#pragma unroll
    for (int i = 0; i < 6; ++i) { float d = v[i] - mu; s2 += d * d; }
#pragma unroll
    for (int o = 32; o; o >>= 1) s2 += __shfl_xor(s2, o, 64);
    float r = rsqrtf(s2 * (1.f / DIM) + 1e-6f);
    __hip_bfloat16* yr = y + (size_t)tok * DIM;
#pragma unroll
    for (int i = 0; i < 6; ++i) {
        int c = lane + 64 * i;
        yr[c] = __float2bfloat16((v[i] - mu) * r * g[c] + bta[c]);
    }
}

// ---------------------------------------------------------------------------
// 64x64 bf16 MFMA GEMM, BK=64 (two stride-32 sub-blocks), 256 threads =
// 4 waves x 32x32 out — the empirical local optimum.
// TRANSOUT: write f32 out[b][c][n] transposed via LDS tile (N must be 384).
// QKV: cols <768 -> bf16 C[M,1152]; cols >=768 (V) -> permuted VT directly.
// ---------------------------------------------------------------------------
template<bool GELU, bool BF16OUT, bool TRANSOUT, bool QKV>
__global__ __launch_bounds__(256) void gemm_mfma(
    const __hip_bfloat16* __restrict__ A,    // [M,K]
    const __hip_bfloat16* __restrict__ BT,   // [N,K]
    const float* __restrict__ bias,
    const float* __restrict__ res,
    void* __restrict__ Cout,
    int M, int N, int K,
    __hip_bfloat16* __restrict__ vtout) {
    __shared__ __align__(16) u16 As[2][64 * 32];
    __shared__ __align__(16) u16 Bs[2][64 * 32];
    int bm = blockIdx.y * 64, bn = blockIdx.x * 64;
    int tid = threadIdx.x;
    int w = tid >> 6, l = tid & 63;
    int m0 = (w >> 1) * 32, n0 = (w & 1) * 32;
    int lm = l & 15, ksel = l >> 4;

    int row = tid >> 2, c16 = tid & 3;
    const __hip_bfloat16* ga = A  + (size_t)(bm + row) * K + c16 * 8;
    const __hip_bfloat16* gb = BT + (size_t)(bn + row) * K + c16 * 8;

    f32x4 acc[2][2] = {};
    for (int k0 = 0; k0 < K; k0 += 64) {
        load_lds16(ga + k0,      &As[0][tid * 8]);
        load_lds16(ga + k0 + 32, &As[1][tid * 8]);
        load_lds16(gb + k0,      &Bs[0][tid * 8]);
        load_lds16(gb + k0 + 32, &Bs[1][tid * 8]);
        __syncthreads();
#pragma unroll
        for (int kk = 0; kk < 2; ++kk) {
            bf16x8 af0 = *(const bf16x8*)&As[kk][(m0 +      lm) * 32 + ksel * 8];
            bf16x8 af1 = *(const bf16x8*)&As[kk][(m0 + 16 + lm) * 32 + ksel * 8];
            bf16x8 bf0 = *(const bf16x8*)&Bs[kk][(n0 +      lm) * 32 + ksel * 8];
            bf16x8 bf1 = *(const bf16x8*)&Bs[kk][(n0 + 16 + lm) * 32 + ksel * 8];
            acc[0][0] = __builtin_amdgcn_mfma_f32_16x16x32_bf16(af0, bf0, acc[0][0], 0, 0, 0);
            acc[0][1] = __builtin_amdgcn_mfma_f32_16x16x32_bf16(af0, bf1, acc[0][1], 0, 0, 0);
            acc[1][0] = __builtin_amdgcn_mfma_f32_16x16x32_bf16(af1, bf0, acc[1][0], 0, 0, 0);
            acc[1][1] = __builtin_amdgcn_mfma_f32_16x16x32_bf16(af1, bf1, acc[1][1], 0, 0, 0);
        }
        __syncthreads();
    }

    if constexpr (TRANSOUT) {
        __shared__ float ct[64 * 65];
#pragma unroll
        for (int i = 0; i < 2; ++i)
#pragma unroll
            for (int j = 0; j < 2; ++j)
#pragma unroll
                for (int r = 0; r < 4; ++r) {
                    int ml = m0 + i * 16 + ksel * 4 + r;
                    int cl = n0 + j * 16 + lm;
                    float v = acc[i][j][r];
                    if (bias) v += bias[bn + cl];
                    if (res)  v += res[(size_t)(bm + ml) * N + bn + cl];
                    ct[ml * 65 + cl] = v;
                }
        __syncthreads();
        int bb = bm >> 11, nb = bm & (NTOK - 1);
        float* outp = (float*)Cout + (size_t)bb * DIM * NTOK + nb;
#pragma unroll
        for (int cl = w; cl < 64; cl += 4)
            outp[(size_t)(bn + cl) * NTOK + l] = ct[l * 65 + cl];
    } else {
#pragma unroll
        for (int i = 0; i < 2; ++i)
#pragma unroll
            for (int j = 0; j < 2; ++j)
#pragma unroll
                for (int r = 0; r < 4; ++r) {
                    int rg = bm + m0 + i * 16 + ksel * 4 + r;
                    int cg = bn + n0 + j * 16 + lm;
                    float v = acc[i][j][r];
                    if (bias) v += bias[cg];
                    if (GELU) v = 0.5f * v * (1.f + erff(v * 0.7071067811865475f));
                    if (res)  v += res[(size_t)rg * N + cg];
                    if constexpr (QKV) {
                        if (cg < 768) {
                            ((__hip_bfloat16*)Cout)[(size_t)rg * 1152 + cg] = __float2bfloat16(v);
                        } else {
                            int c = cg - 768, hh = c / 48, dd = c - hh * 48;
                            int bb = rg >> 11, n = rg & (NTOK - 1);
                            int kk = n & 127;
                            int pos = ((kk >> 6) << 6) + ((kk & 15) << 2) + ((kk >> 4) & 3);
                            vtout[((size_t)(bb * NHEAD + hh) * 48 + dd) * 2048
                                  + (n & ~127) + pos] = __float2bfloat16(v);
                        }
                    } else if constexpr (BF16OUT) {
                        ((__hip_bfloat16*)Cout)[(size_t)rg * N + cg] = __float2bfloat16(v);
                    } else {
                        ((float*)Cout)[(size_t)rg * N + cg] = v;
                    }
                }
    }
}

// ---------------------------------------------------------------------------
// bf16 MFMA flash attention (round-12 optimum), 128-key tiles, one-pass
// softmax, 512 threads = 8 waves (qc = w>>1, kh = w&1), Ps overlays Qs.
// ---------------------------------------------------------------------------
#define ATK 128
#define PSTR 136   // row stride in u16; rows 16B-aligned
__global__ __launch_bounds__(512, 6) void attn_mfma(
    const u16* __restrict__ qkv,             // bf16 [TOKS][1152] (Q,K valid)
    const u16* __restrict__ vt,              // bf16 [16][48][2048] (permuted keys)
    __hip_bfloat16* __restrict__ outp) {     // bf16 [TOKS][DIM]
    __shared__ __align__(16) u16 PQ[64 * PSTR];   // Qs (stride 72) then Ps
    __shared__ __align__(16) u16 Ks[128 * 72];
    __shared__ __align__(16) u16 Vs[48 * PSTR];
    const int q0 = blockIdx.x * 64;
    const int h = blockIdx.y, b = blockIdx.z;
    const int tid = threadIdx.x;
    const int w = tid >> 6, l = tid & 63, lm = l & 15, quad = l >> 4;
    const int qc = w >> 1, kh = w & 1;

    for (int idx = tid; idx < 128; idx += 512) {
        int r = idx >> 1, c = idx & 1;
        *(uint4*)&PQ[r * 72 + 48 + c * 8] = uint4{0, 0, 0, 0};
    }
    for (int idx = tid; idx < 256; idx += 512) {
        int r = idx >> 1, c = idx & 1;
        *(uint4*)&Ks[r * 72 + 48 + c * 8] = uint4{0, 0, 0, 0};
    }
    const u16* qbase = qkv + (size_t)(b * NTOK + q0) * 1152 + h * 48;
    for (int idx = tid; idx < 384; idx += 512) {
        int r = idx / 6, c = idx % 6;
        *(uint4*)&PQ[r * 72 + c * 8] = *(const uint4*)(qbase + (size_t)r * 1152 + c * 8);
    }
    __syncthreads();

    bf16x8 aq0 = *(const bf16x8*)&PQ[(qc * 16 + lm) * 72 +  0 + quad * 8];
    bf16x8 aq1 = *(const bf16x8*)&PQ[(qc * 16 + lm) * 72 + 32 + quad * 8];

    float l_i[4] = {0.f, 0.f, 0.f, 0.f};
    f32x4 o_acc[3] = {};

    const u16* kbase = qkv + (size_t)(b * NTOK) * 1152 + 384 + h * 48;
    const u16* vbase = vt + (size_t)(b * NHEAD + h) * 48 * 2048;
    const float sc2 = 0.14433756729740643f * 1.4426950408889634f;  // scale*log2e

    for (int kt = 0; kt < NTOK / ATK; ++kt) {
        __syncthreads();
#pragma unroll
        for (int idx = tid; idx < 768; idx += 512) {
            int r = idx / 6, c = idx % 6;
            *(uint4*)&Ks[r * 72 + c * 8] =
                *(const uint4*)(kbase + (size_t)(kt * ATK + r) * 1152 + c * 8);
        }
#pragma unroll
        for (int idx = tid; idx < 768; idx += 512) {
            int d = idx >> 4, c = idx & 15;
            *(uint4*)&Vs[d * PSTR + c * 8] =
                *(const uint4*)(vbase + (size_t)d * 2048 + kt * ATK + c * 8);
        }
        __syncthreads();

        f32x4 s[4];
#pragma unroll
        for (int ntp = 0; ntp < 4; ++ntp) {
            int nt = kh * 4 + ntp;
            bf16x8 kf0 = *(const bf16x8*)&Ks[(nt * 16 + lm) * 72 +  0 + quad * 8];
            bf16x8 kf1 = *(const bf16x8*)&Ks[(nt * 16 + lm) * 72 + 32 + quad * 8];
            f32x4 t = {};
            t = __builtin_amdgcn_mfma_f32_16x16x32_bf16(aq0, kf0, t, 0, 0, 0);
            t = __builtin_amdgcn_mfma_f32_16x16x32_bf16(aq1, kf1, t, 0, 0, 0);
            s[ntp] = t;
        }

#pragma unroll
        for (int r = 0; r < 4; ++r) {
            u16 pr[4];
#pragma unroll
            for (int ntp = 0; ntp < 4; ++ntp) {
                float p = exp2f(s[ntp][r] * sc2);
                l_i[r] += p;
                bfu cv; cv.h = __float2bfloat16(p);
                pr[ntp] = cv.u;
            }
            *(uint2*)&PQ[(qc * 16 + quad * 4 + r) * PSTR + kh * 64 + lm * 4] =
                *(const uint2*)pr;
        }

#pragma unroll
        for (int ksp = 0; ksp < 2; ++ksp) {
            int ks = kh * 2 + ksp;
            bf16x8 pf = *(const bf16x8*)&PQ[(qc * 16 + lm) * PSTR + ks * 32 + quad * 8];
#pragma unroll
            for (int nt = 0; nt < 3; ++nt) {
                bf16x8 vf = *(const bf16x8*)&Vs[(nt * 16 + lm) * PSTR + ks * 32 + quad * 8];
                o_acc[nt] = __builtin_amdgcn_mfma_f32_16x16x32_bf16(pf, vf, o_acc[nt], 0, 0, 0);
            }
        }
    }

    __syncthreads();
    float* red = (float*)Ks;
    if (kh == 1) {
        f32x4* base = (f32x4*)&red[(qc * 64 + l) * 16];
        base[0] = o_acc[0]; base[1] = o_acc[1]; base[2] = o_acc[2];
        f32x4 lv; lv[0] = l_i[0]; lv[1] = l_i[1]; lv[2] = l_i[2]; lv[3] = l_i[3];
        base[3] = lv;
    }
    __syncthreads();
    if (kh == 0) {
        f32x4* base = (f32x4*)&red[(qc * 64 + l) * 16];
        o_acc[0] += base[0]; o_acc[1] += base[1]; o_acc[2] += base[2];
        f32x4 lv = base[3];
#pragma unroll
        for (int r = 0; r < 4; ++r) {
            float lsum = l_i[r] + lv[r];
#pragma unroll
            for (int o = 8; o; o >>= 1) lsum += __shfl_xor(lsum, o, 64);
            float inv = 1.f / lsum;
#pragma unroll
            for (int nt = 0; nt < 3; ++nt)
                outp[(size_t)(b * NTOK + q0 + qc * 16 + quad * 4 + r) * DIM
                     + h * 48 + nt * 16 + lm]
                    = __float2bfloat16(o_acc[nt][r] * inv);
        }
    }
}

// ---------------------------------------------------------------------------
extern "C" void kernel_launch(void* const* d_in, const int* in_sizes, int n_in,
                              void* d_out, int out_size, void* d_ws, size_t ws_size,
                              hipStream_t stream) {
    const float* x    = (const float*)d_in[0];
    const float* g1   = (const float*)d_in[1];
    const float* b1   = (const float*)d_in[2];
    const float* Wqkv = (const float*)d_in[3];
    const float* Wo   = (const float*)d_in[4];
    const float* bo   = (const float*)d_in[5];
    const float* g2   = (const float*)d_in[6];
    const float* b2   = (const float*)d_in[7];
    const float* W1   = (const float*)d_in[8];
    const float* b1m  = (const float*)d_in[9];
    const float* W2   = (const float*)d_in[10];
    const float* b2m  = (const float*)d_in[11];
    float* out = (float*)d_out;

    char* p = (char*)d_ws;
    float* bufH = (float*)p;                       p += (size_t)TOKS * DIM * 4;      // f32 [4096,384]
    char* qkvp = p;
    __hip_bfloat16* bufQKVb = (__hip_bfloat16*)p;  p += (size_t)TOKS * 3 * DIM * 2;  // bf16 [4096,1152]
    __hip_bfloat16* bufVT   = (__hip_bfloat16*)p;  p += (size_t)TOKS * DIM * 2;      // bf16 [16,48,2048]
    __hip_bfloat16* bufNb   = (__hip_bfloat16*)p;  p += (size_t)TOKS * DIM * 2;      // bf16 [4096,384]
    __hip_bfloat16* bufAb   = (__hip_bfloat16*)p;  p += (size_t)TOKS * DIM * 2;      // bf16 [4096,384]
    __hip_bfloat16* WqkvT   = (__hip_bfloat16*)p;  p += (size_t)3 * DIM * DIM * 2;   // [1152,384]
    __hip_bfloat16* WoT     = (__hip_bfloat16*)p;  p += (size_t)DIM * DIM * 2;       // [384,384]
    __hip_bfloat16* W1T     = (__hip_bfloat16*)p;  p += (size_t)HIDDEN * DIM * 2;    // [1536,384]
    __hip_bfloat16* W2T     = (__hip_bfloat16*)p;  p += (size_t)DIM * HIDDEN * 2;    // [384,1536]
    __hip_bfloat16* bufHIDb = (__hip_bfloat16*)qkvp;  // bf16 [4096,1536] overlays QKV+VT

    // 0. weight transposes + input transpose/LN1 (one dispatch)
    prep<<<1728 + 128, 256, 0, stream>>>(Wqkv, Wo, W1, W2, WqkvT, WoT, W1T, W2T,
                                         x, g1, b1, bufH, bufNb);
    // 1. QKV projection: Q,K -> bufQKVb; V -> bufVT (permuted) directly
    gemm_mfma<false, true, false, true><<<dim3(3 * DIM / 64, TOKS / 64), 256, 0, stream>>>(
        bufNb, WqkvT, nullptr, nullptr, bufQKVb, TOKS, 3 * DIM, DIM, bufVT);
    // 2. MFMA flash attention -> bf16 (512 threads, 3 blocks/CU)
    attn_mfma<<<dim3(NTOK / 64, NHEAD, BATCH), 512, 0, stream>>>(
        (const u16*)bufQKVb, (const u16*)bufVT, bufAb);
    // 3. output projection + bias + residual -> f32 bufH (in place)
    gemm_mfma<false, false, false, false><<<dim3(DIM / 64, TOKS / 64), 256, 0, stream>>>(
        bufAb, WoT, bo, bufH, bufH, TOKS, DIM, DIM, nullptr);
    // 4. LN2 -> bf16
    ln_kernel<<<TOKS / 4, 256, 0, stream>>>(bufH, g2, b2, bufNb);
    // 5. MLP up + GELU -> bf16 hidden
    gemm_mfma<true, true, false, false><<<dim3(HIDDEN / 64, TOKS / 64), 256, 0, stream>>>(
        bufNb, W1T, b1m, nullptr, bufHIDb, TOKS, HIDDEN, DIM, nullptr);
    // 6. MLP down + bias + residual -> out (transposed write, f32)
    gemm_mfma<false, false, true, false><<<dim3(DIM / 64, TOKS / 64), 256, 0, stream>>>(
        bufHIDb, W2T, b2m, bufH, out, TOKS, DIM, HIDDEN, nullptr);
}